// Round 11
// baseline (1598.194 us; speedup 1.0000x reference)
//
#include <hip/hip_runtime.h>

#define B_  64
#define T_  512
#define D_  64
#define U_  256
#define G4  1024   // 4*U
#define NT  512    // 8 waves, 2 per SIMD -> 256 unified regs/wave

typedef _Float16 f16x8 __attribute__((ext_vector_type(8)));   // 16 B = 4 regs
typedef float    f32x4 __attribute__((ext_vector_type(4)));

__device__ __forceinline__ float sigmoidf_(float z) {
    return 1.f / (1.f + __expf(-z));
}

// ---------------------------------------------------------------------------
// Kernel 1: xz[t*B+b][g] = bias[g] + sum_d x[b][t][d] * W[d][g]   (fp32 exact)
// ---------------------------------------------------------------------------
__global__ __launch_bounds__(256) void xz_kernel(const float* __restrict__ x,
                                                 const float* __restrict__ W,
                                                 const float* __restrict__ bias,
                                                 float* __restrict__ xz) {
    __shared__ float xt[16][D_];
    const int g    = blockIdx.x * 256 + threadIdx.x;
    const int row0 = blockIdx.y * 16;

    #pragma unroll
    for (int j = 0; j < 4; ++j) {
        int e = threadIdx.x + 256 * j;
        int r = e >> 6, d = e & 63;
        int row = row0 + r;
        int t = row >> 6, bb = row & 63;        // row = t*64 + b
        xt[r][d] = x[((size_t)bb * T_ + t) * D_ + d];
    }
    __syncthreads();

    float acc[16];
    #pragma unroll
    for (int r = 0; r < 16; ++r) acc[r] = 0.f;

    for (int d = 0; d < D_; ++d) {
        float wv = W[(size_t)d * G4 + g];
        #pragma unroll
        for (int r = 0; r < 16; ++r) acc[r] += xt[r][d] * wv;
    }

    float bg = bias[g];
    #pragma unroll
    for (int r = 0; r < 16; ++r)
        xz[(size_t)(row0 + r) * G4 + g] = acc[r] + bg;
}

// ---------------------------------------------------------------------------
// Kernel 2: MFMA LSTM scan, ONE barrier per step.
// Wave w owns global cols {256q + 32w + 16s + li : q=0..3, s=0..1} so the 4
// gate values of unit u = 32w + 16s + li all land in wave-w accumulators ->
// gates are wave-local (no z LDS round-trip). h double-buffered in LDS.
// B-frags: 45/wave pinned in AGPRs ("+a" tie, round-10-verified no-spill),
// 19/wave in LDS. A = h broadcast to all 16 rows (round-9-verified).
// ---------------------------------------------------------------------------

struct Smem {
    _Float16 h16[2][256];       // 1 KB   (double-buffered h)
    float    pdp[2][8];         // 64 B   (per-wave dense partials, dbuf)
    f16x8    bl[8][19][64];     // 152 KB (LDS-resident B frags)
};                              // 156736 B (< 163840)

// B frag element: lane (gg, li), elem e -> U[32*kt + 8*gg + e][16*ntg + li]
__device__ __forceinline__ f16x8 load_bfrag(const float* __restrict__ Um,
                                            int ntg, int kt, int gg, int li) {
    const float* p = Um + (size_t)(32 * kt + 8 * gg) * G4 + 16 * ntg + li;
    f16x8 v;
    #pragma unroll
    for (int e = 0; e < 8; ++e) v[e] = (_Float16)p[(size_t)e * G4];
    return v;
}

// local tile nl = 2q+s  ->  global 16-col tile index
#define NTG(NL) (16 * ((NL) >> 1) + 2 * w + ((NL) & 1))

// ---- 45 AGPR-resident B frags: kt=2 nl=3..7, kt=3..7 nl=0..7 ----
#define FOR_AG(X) \
    X(2,3) X(2,4) X(2,5) X(2,6) X(2,7) \
    X(3,0) X(3,1) X(3,2) X(3,3) X(3,4) X(3,5) X(3,6) X(3,7) \
    X(4,0) X(4,1) X(4,2) X(4,3) X(4,4) X(4,5) X(4,6) X(4,7) \
    X(5,0) X(5,1) X(5,2) X(5,3) X(5,4) X(5,5) X(5,6) X(5,7) \
    X(6,0) X(6,1) X(6,2) X(6,3) X(6,4) X(6,5) X(6,6) X(6,7) \
    X(7,0) X(7,1) X(7,2) X(7,3) X(7,4) X(7,5) X(7,6) X(7,7)

#define DB(K,N) f16x8 bF_##K##_##N;
#define IB(K,N) { bF_##K##_##N = load_bfrag(Um, NTG(N), (K), gg, li); \
                  asm("" : "+a"(bF_##K##_##N)); }

#define MMV(N, BV) acc##N = __builtin_amdgcn_mfma_f32_16x16x32_f16(av, (BV), acc##N, 0, 0, 0);
#define MMR(K, N)  acc##N = __builtin_amdgcn_mfma_f32_16x16x32_f16(av, bF_##K##_##N, acc##N, 0, 0, 0);

#define MKLDS(KT, FB) { \
    f16x8 av = *(const f16x8*)&hp[32 * (KT) + 8 * gg]; \
    { f16x8 bv = sm.bl[w][(FB)+0][lane]; MMV(0, bv) } \
    { f16x8 bv = sm.bl[w][(FB)+1][lane]; MMV(1, bv) } \
    { f16x8 bv = sm.bl[w][(FB)+2][lane]; MMV(2, bv) } \
    { f16x8 bv = sm.bl[w][(FB)+3][lane]; MMV(3, bv) } \
    { f16x8 bv = sm.bl[w][(FB)+4][lane]; MMV(4, bv) } \
    { f16x8 bv = sm.bl[w][(FB)+5][lane]; MMV(5, bv) } \
    { f16x8 bv = sm.bl[w][(FB)+6][lane]; MMV(6, bv) } \
    { f16x8 bv = sm.bl[w][(FB)+7][lane]; MMV(7, bv) } }

#define MKREG(KT) { \
    f16x8 av = *(const f16x8*)&hp[32 * (KT) + 8 * gg]; \
    MMR(KT,0) MMR(KT,1) MMR(KT,2) MMR(KT,3) \
    MMR(KT,4) MMR(KT,5) MMR(KT,6) MMR(KT,7) }

__global__
__attribute__((amdgpu_flat_work_group_size(NT, NT), amdgpu_waves_per_eu(2, 2)))
void lstm_kernel(
        const float* __restrict__ Um,
        const float* __restrict__ dw,
        const float* __restrict__ dbp,
        const float* __restrict__ xz,
        float* __restrict__ out) {
    __shared__ Smem sm;

    const int tau  = threadIdx.x;
    const int b    = blockIdx.x;
    const int w    = tau >> 6;          // wave 0..7
    const int lane = tau & 63;
    const int gg   = (tau >> 4) & 3;    // 16-lane k-group
    const int li   = tau & 15;
    const int sel  = (lane >> 4) & 1;   // which 16-col half of the 32-unit block
    const int u    = 32 * w + 16 * sel + li;   // unit owned (lanes>=32 duplicate)

    // ---- one-time: AGPR-pinned B frags (new wave-local column mapping) ----
    FOR_AG(DB)
    FOR_AG(IB)
    __builtin_amdgcn_sched_barrier(0);

    // ---- one-time: LDS B frags (f 0..7 -> kt0, 8..15 -> kt1, 16..18 -> kt2)
    #pragma unroll
    for (int f = 0; f < 19; ++f) {
        const int kt = (f < 8) ? 0 : (f < 16) ? 1 : 2;
        const int nl = (f < 16) ? (f & 7) : (f - 16);
        sm.bl[w][f][lane] = load_bfrag(Um, NTG(nl), kt, gg, li);
    }

    if (tau < U_) sm.h16[0][tau] = (_Float16)0.f;

    const float dwr = (lane < 32) ? dw[u] : 0.f;   // lanes>=32 are duplicates
    const float db0 = dbp[0];
    float c_state = 0.f;

    // xz for t=0 (cols 256q + u)
    {
        const float* xp = xz + (size_t)b * G4;
        // nothing else needed; loaded below
    }
    const float* xp0 = xz + (size_t)b * G4;
    float xq0 = xp0[u], xq1 = xp0[256 + u], xq2 = xp0[512 + u], xq3 = xp0[768 + u];
    __syncthreads();

    for (int t = 0; t < T_; ++t) {
        const int cur = t & 1, nxt = cur ^ 1;

        // ---- rotating wave stores out[t-1] (pdp dbuf -> race-free) ----
        if (t > 0 && w == ((t - 1) & 7)) {
            float s = (lane < 8) ? sm.pdp[(t - 1) & 1][lane] : 0.f;
            s += __shfl_down(s, 4); s += __shfl_down(s, 2); s += __shfl_down(s, 1);
            if (lane == 0) out[(size_t)b * T_ + (t - 1)] = s + db0;
        }

        // ---- prefetch xz for t+1 NOW; barrier comes a full MFMA phase later
        const int tn = (t + 1 < T_) ? t + 1 : t;
        const float* xp = xz + ((size_t)tn * B_ + b) * G4;
        float xn0 = xp[u], xn1 = xp[256 + u], xn2 = xp[512 + u], xn3 = xp[768 + u];
        __builtin_amdgcn_sched_barrier(0);   // pin load issue before MFMAs

        // ---- MFMA phase: this wave's 8 col-tiles x K=256 ----
        const _Float16* hp = &sm.h16[cur][0];
        f32x4 acc0 = {0.f,0.f,0.f,0.f}, acc1 = {0.f,0.f,0.f,0.f};
        f32x4 acc2 = {0.f,0.f,0.f,0.f}, acc3 = {0.f,0.f,0.f,0.f};
        f32x4 acc4 = {0.f,0.f,0.f,0.f}, acc5 = {0.f,0.f,0.f,0.f};
        f32x4 acc6 = {0.f,0.f,0.f,0.f}, acc7 = {0.f,0.f,0.f,0.f};

        MKLDS(0, 0)                      // kt=0, LDS frags 0..7
        MKLDS(1, 8)                      // kt=1, LDS frags 8..15
        {                                // kt=2: nl0..2 LDS, nl3..7 AGPR
            f16x8 av = *(const f16x8*)&hp[64 + 8 * gg];
            { f16x8 bv = sm.bl[w][16][lane]; MMV(0, bv) }
            { f16x8 bv = sm.bl[w][17][lane]; MMV(1, bv) }
            { f16x8 bv = sm.bl[w][18][lane]; MMV(2, bv) }
            MMR(2,3) MMR(2,4) MMR(2,5) MMR(2,6) MMR(2,7)
        }
        MKREG(3) MKREG(4) MKREG(5) MKREG(6) MKREG(7)

        // ---- wave-local gates: unit u's 4 gates are in acc(2q+sel)[0] ----
        // (A rows identical -> all 4 acc elems equal; elem 0 valid on every lane)
        float zi = (sel ? acc1[0] : acc0[0]) + xq0;
        float zf = (sel ? acc3[0] : acc2[0]) + xq1;
        float zg = (sel ? acc5[0] : acc4[0]) + xq2;
        float zo = (sel ? acc7[0] : acc6[0]) + xq3;
        float ig = sigmoidf_(zi);
        float fg = sigmoidf_(zf);
        float gv = fmaxf(zg, 0.f);
        float og = sigmoidf_(zo);
        c_state = fg * c_state + ig * gv;
        float h = og * fmaxf(c_state, 0.f);
        if (lane < 32) sm.h16[nxt][u] = (_Float16)h;

        // dense partial: lanes>=32 have dwr=0 (duplicates contribute nothing)
        float pv = h * dwr;
        pv += __shfl_down(pv, 32); pv += __shfl_down(pv, 16);
        pv += __shfl_down(pv, 8);  pv += __shfl_down(pv, 4);
        pv += __shfl_down(pv, 2);  pv += __shfl_down(pv, 1);
        if (lane == 0) sm.pdp[cur][w] = pv;

        __syncthreads();                 // ONE barrier: h[nxt], pdp visible

        xq0 = xn0; xq1 = xn1; xq2 = xn2; xq3 = xn3;
    }

    // ---- epilogue: out[T-1] ----
    if (w == ((T_ - 1) & 7)) {
        float s = (lane < 8) ? sm.pdp[(T_ - 1) & 1][lane] : 0.f;
        s += __shfl_down(s, 4); s += __shfl_down(s, 2); s += __shfl_down(s, 1);
        if (lane == 0) out[(size_t)b * T_ + (T_ - 1)] = s + db0;
    }
}

// ---------------------------------------------------------------------------
// Fallback (no workspace): streaming kernel, correctness only.
// ---------------------------------------------------------------------------
__global__ __launch_bounds__(1024) void lstm_fallback(
        const float* __restrict__ x,  const float* __restrict__ W,
        const float* __restrict__ Um, const float* __restrict__ bias,
        const float* __restrict__ dw, const float* __restrict__ dbp,
        float* __restrict__ out) {
    __shared__ float h_s[U_];
    __shared__ float z_s2[G4];
    __shared__ float pd_s2[U_];
    const int g = threadIdx.x;
    const int b = blockIdx.x;
    const float bg  = bias[g];
    const float dwr = (g < U_) ? dw[g] : 0.f;
    const float db0 = dbp[0];
    float c = 0.f;
    if (g < U_) h_s[g] = 0.f;
    __syncthreads();
    const float* Ucol = Um + g;
    for (int t = 0; t < T_; ++t) {
        float acc = bg;
        const float* xrow = x + ((size_t)b * T_ + t) * D_;
        for (int d = 0; d < D_; ++d) acc += xrow[d] * W[(size_t)d * G4 + g];
        for (int k = 0; k < U_; ++k) acc += h_s[k] * Ucol[(size_t)k * G4];
        z_s2[g] = acc;
        __syncthreads();
        if (g < U_) {
            float ig = sigmoidf_(z_s2[g]);
            float fg = sigmoidf_(z_s2[U_ + g]);
            float gg2 = fmaxf(z_s2[2 * U_ + g], 0.f);
            float og = sigmoidf_(z_s2[3 * U_ + g]);
            c = fg * c + ig * gg2;
            float h = og * fmaxf(c, 0.f);
            h_s[g] = h; pd_s2[g] = h * dwr;
        }
        __syncthreads();
        if (g < 64) {
            float s = pd_s2[g] + pd_s2[g + 64] + pd_s2[g + 128] + pd_s2[g + 192];
            #pragma unroll
            for (int off = 32; off > 0; off >>= 1) s += __shfl_down(s, off);
            if (g == 0) out[(size_t)b * T_ + t] = s + db0;
        }
        __syncthreads();
    }
}

// ---------------------------------------------------------------------------
extern "C" void kernel_launch(void* const* d_in, const int* in_sizes, int n_in,
                              void* d_out, int out_size, void* d_ws, size_t ws_size,
                              hipStream_t stream) {
    const float* x    = (const float*)d_in[0];
    const float* W    = (const float*)d_in[1];
    const float* Um   = (const float*)d_in[2];
    const float* bias = (const float*)d_in[3];
    const float* dw   = (const float*)d_in[4];
    const float* db   = (const float*)d_in[5];
    float* out = (float*)d_out;

    const size_t need = (size_t)T_ * B_ * G4 * sizeof(float);   // 128 MiB
    if (ws_size >= need) {
        float* xz = (float*)d_ws;
        dim3 gridX(G4 / 256, (T_ * B_) / 16);
        xz_kernel<<<gridX, 256, 0, stream>>>(x, W, bias, xz);
        lstm_kernel<<<B_, NT, 0, stream>>>(Um, dw, db, xz, out);
    } else {
        lstm_fallback<<<B_, 1024, 0, stream>>>(x, W, Um, bias, dw, db, out);
    }
}

// Round 12
// 1089.777 us; speedup vs baseline: 1.4665x; 1.4665x over previous
//
#include <hip/hip_runtime.h>

#define B_  64
#define T_  512
#define D_  64
#define U_  256
#define G4  1024   // 4*U
#define NT  512    // 8 waves, 2 per SIMD -> 256 unified regs/wave

typedef _Float16 f16x8 __attribute__((ext_vector_type(8)));   // 16 B = 4 regs
typedef float    f32x4 __attribute__((ext_vector_type(4)));

__device__ __forceinline__ float sigmoidf_(float z) {
    return 1.f / (1.f + __expf(-z));
}

// ---------------------------------------------------------------------------
// Kernel 1: xz[t*B+b][g] = bias[g] + sum_d x[b][t][d] * W[d][g]   (fp32 exact)
// ---------------------------------------------------------------------------
__global__ __launch_bounds__(256) void xz_kernel(const float* __restrict__ x,
                                                 const float* __restrict__ W,
                                                 const float* __restrict__ bias,
                                                 float* __restrict__ xz) {
    __shared__ float xt[16][D_];
    const int g    = blockIdx.x * 256 + threadIdx.x;
    const int row0 = blockIdx.y * 16;

    #pragma unroll
    for (int j = 0; j < 4; ++j) {
        int e = threadIdx.x + 256 * j;
        int r = e >> 6, d = e & 63;
        int row = row0 + r;
        int t = row >> 6, bb = row & 63;        // row = t*64 + b
        xt[r][d] = x[((size_t)bb * T_ + t) * D_ + d];
    }
    __syncthreads();

    float acc[16];
    #pragma unroll
    for (int r = 0; r < 16; ++r) acc[r] = 0.f;

    for (int d = 0; d < D_; ++d) {
        float wv = W[(size_t)d * G4 + g];
        #pragma unroll
        for (int r = 0; r < 16; ++r) acc[r] += xt[r][d] * wv;
    }

    float bg = bias[g];
    #pragma unroll
    for (int r = 0; r < 16; ++r)
        xz[(size_t)(row0 + r) * G4 + g] = acc[r] + bg;
}

// ---------------------------------------------------------------------------
// Kernel 2: MFMA LSTM scan (round-10 structure + early xz issue).
// One WG (512 thr, 8 waves) per batch element. Wave w owns cols
// [128w, 128w+128) = 8 N-tiles. Per wave, 64 B-frags:
//   45 pinned in AGPRs ("+a" tie, verified no-spill),
//   19 in LDS (152 KB, conflict-free 16 B/lane reads).
// A = h broadcast to all 16 rows; A and B share the same (k-group, elem)->k
// load pattern so the HW k-map cancels (round-9-verified construction).
// xz[t] loads are issued at the TOP of the MFMA phase so the vmcnt(0) drain
// at the z-barrier (~1400 cyc later) finds them complete (T14 split).
// ---------------------------------------------------------------------------

struct Smem {
    _Float16 h16[256];          // 512 B
    float    z[G4];             // 4 KB
    float    pd[U_];            // 1 KB
    f16x8    bl[8][19][64];     // 8 waves x 19 frags x 64 lanes x 16 B = 152 KB
};                              // total 161280 B  (< 163840)

// B frag element: lane (gg, li), elem e -> U[32*kt + 8*gg + e][16*ntg + li]
__device__ __forceinline__ f16x8 load_bfrag(const float* __restrict__ Um,
                                            int ntg, int kt, int gg, int li) {
    const float* p = Um + (size_t)(32 * kt + 8 * gg) * G4 + 16 * ntg + li;
    f16x8 v;
    #pragma unroll
    for (int e = 0; e < 8; ++e) v[e] = (_Float16)p[(size_t)e * G4];
    return v;
}

// ---- 45 AGPR-resident B frags: kt=2 nt=3..7, kt=3..7 nt=0..7 ----
#define FOR_AG(X) \
    X(2,3) X(2,4) X(2,5) X(2,6) X(2,7) \
    X(3,0) X(3,1) X(3,2) X(3,3) X(3,4) X(3,5) X(3,6) X(3,7) \
    X(4,0) X(4,1) X(4,2) X(4,3) X(4,4) X(4,5) X(4,6) X(4,7) \
    X(5,0) X(5,1) X(5,2) X(5,3) X(5,4) X(5,5) X(5,6) X(5,7) \
    X(6,0) X(6,1) X(6,2) X(6,3) X(6,4) X(6,5) X(6,6) X(6,7) \
    X(7,0) X(7,1) X(7,2) X(7,3) X(7,4) X(7,5) X(7,6) X(7,7)

#define DB(K,N) f16x8 bF_##K##_##N;
// load, then pin to the AGPR class with a zero-instruction constraint tie
#define IB(K,N) { bF_##K##_##N = load_bfrag(Um, w8 + (N), (K), gg, li); \
                  asm("" : "+a"(bF_##K##_##N)); }

#define MMV(N, BV) acc##N = __builtin_amdgcn_mfma_f32_16x16x32_f16(av, (BV), acc##N, 0, 0, 0);
#define MMR(K, N)  acc##N = __builtin_amdgcn_mfma_f32_16x16x32_f16(av, bF_##K##_##N, acc##N, 0, 0, 0);

#define MKLDS(KT, FB) { \
    f16x8 av = *(const f16x8*)&sm.h16[32 * (KT) + 8 * gg]; \
    { f16x8 bv = sm.bl[w][(FB)+0][lane]; MMV(0, bv) } \
    { f16x8 bv = sm.bl[w][(FB)+1][lane]; MMV(1, bv) } \
    { f16x8 bv = sm.bl[w][(FB)+2][lane]; MMV(2, bv) } \
    { f16x8 bv = sm.bl[w][(FB)+3][lane]; MMV(3, bv) } \
    { f16x8 bv = sm.bl[w][(FB)+4][lane]; MMV(4, bv) } \
    { f16x8 bv = sm.bl[w][(FB)+5][lane]; MMV(5, bv) } \
    { f16x8 bv = sm.bl[w][(FB)+6][lane]; MMV(6, bv) } \
    { f16x8 bv = sm.bl[w][(FB)+7][lane]; MMV(7, bv) } }

#define MKREG(KT) { \
    f16x8 av = *(const f16x8*)&sm.h16[32 * (KT) + 8 * gg]; \
    MMR(KT,0) MMR(KT,1) MMR(KT,2) MMR(KT,3) \
    MMR(KT,4) MMR(KT,5) MMR(KT,6) MMR(KT,7) }

__global__
__attribute__((amdgpu_flat_work_group_size(NT, NT), amdgpu_waves_per_eu(2, 2)))
void lstm_kernel(
        const float* __restrict__ Um,
        const float* __restrict__ dw,
        const float* __restrict__ dbp,
        const float* __restrict__ xz,
        float* __restrict__ out) {
    __shared__ Smem sm;

    const int tau  = threadIdx.x;
    const int b    = blockIdx.x;
    const int w    = tau >> 6;          // wave 0..7
    const int lane = tau & 63;
    const int gg   = (tau >> 4) & 3;    // 16-lane k-group
    const int li   = tau & 15;
    const int w8   = 8 * w;             // global N-tile base for this wave

    // ---- one-time: AGPR-pinned B frags ----
    FOR_AG(DB)
    FOR_AG(IB)
    __builtin_amdgcn_sched_barrier(0);

    // ---- one-time: LDS B frags (f 0..7 -> kt0, 8..15 -> kt1, 16..18 -> kt2 nt0..2)
    #pragma unroll
    for (int f = 0; f < 19; ++f) {
        const int kt = (f < 8) ? 0 : (f < 16) ? 1 : 2;
        const int nt = (f < 16) ? (f & 7) : (f - 16);
        sm.bl[w][f][lane] = load_bfrag(Um, w8 + nt, kt, gg, li);
    }

    if (tau < U_) sm.h16[tau] = (_Float16)0.f;

    const float dwr = (tau < U_) ? dw[tau] : 0.f;
    const float db0 = dbp[0];
    float c_state = 0.f;

    __syncthreads();

    for (int t = 0; t < T_; ++t) {
        // ---- issue xz[t] loads NOW; consumed after barrier #1, ~1400 cyc away.
        // The vmcnt(0) drain at barrier #1 finds them complete -> free.
        float xq0 = 0.f, xq1 = 0.f, xq2 = 0.f, xq3 = 0.f;
        if (tau < U_) {
            const float* xp = xz + ((size_t)t * B_ + b) * G4;
            xq0 = xp[tau];
            xq1 = xp[U_ + tau];
            xq2 = xp[2 * U_ + tau];
            xq3 = xp[3 * U_ + tau];
        }
        __builtin_amdgcn_sched_barrier(0);   // keep load issue above the MFMAs

        // ---- MFMA phase: z = h @ U for this wave's 128 cols ----
        f32x4 acc0 = {0.f,0.f,0.f,0.f}, acc1 = {0.f,0.f,0.f,0.f};
        f32x4 acc2 = {0.f,0.f,0.f,0.f}, acc3 = {0.f,0.f,0.f,0.f};
        f32x4 acc4 = {0.f,0.f,0.f,0.f}, acc5 = {0.f,0.f,0.f,0.f};
        f32x4 acc6 = {0.f,0.f,0.f,0.f}, acc7 = {0.f,0.f,0.f,0.f};

        MKLDS(0, 0)                      // kt=0, LDS frags 0..7
        MKLDS(1, 8)                      // kt=1, LDS frags 8..15
        {                                // kt=2: nt0..2 LDS frags 16..18, nt3..7 AGPR
            f16x8 av = *(const f16x8*)&sm.h16[64 + 8 * gg];
            { f16x8 bv = sm.bl[w][16][lane]; MMV(0, bv) }
            { f16x8 bv = sm.bl[w][17][lane]; MMV(1, bv) }
            { f16x8 bv = sm.bl[w][18][lane]; MMV(2, bv) }
            MMR(2,3) MMR(2,4) MMR(2,5) MMR(2,6) MMR(2,7)
        }
        MKREG(3) MKREG(4) MKREG(5) MKREG(6) MKREG(7)

        // D rows all identical (A rows broadcast) -> lanes 0..15, elem .x
        if (lane < 16) {
            const int zb = 128 * w + lane;
            sm.z[zb]       = acc0.x;  sm.z[zb + 16]  = acc1.x;
            sm.z[zb + 32]  = acc2.x;  sm.z[zb + 48]  = acc3.x;
            sm.z[zb + 64]  = acc4.x;  sm.z[zb + 80]  = acc5.x;
            sm.z[zb + 96]  = acc6.x;  sm.z[zb + 112] = acc7.x;
        }
        __syncthreads();                 // barrier #1: z ready (xz loads landed)

        // ---- gates + state update (threads tau < 256, u = tau) ----
        if (tau < U_) {
            float zi = sm.z[tau]            + xq0;
            float zf = sm.z[U_ + tau]       + xq1;
            float zg = sm.z[2 * U_ + tau]   + xq2;
            float zo = sm.z[3 * U_ + tau]   + xq3;
            float ig = sigmoidf_(zi);
            float fg = sigmoidf_(zf);
            float gv = fmaxf(zg, 0.f);
            float og = sigmoidf_(zo);
            c_state = fg * c_state + ig * gv;
            float h = og * fmaxf(c_state, 0.f);
            sm.h16[tau] = (_Float16)h;
            sm.pd[tau]  = h * dwr;
        }
        __syncthreads();                 // barrier #2: h, pd ready

        // ---- dense: sigma[b][t] = sum_u h[u]*dw[u] + db ----
        if (tau < 64) {
            float s = sm.pd[tau] + sm.pd[tau + 64] + sm.pd[tau + 128] + sm.pd[tau + 192];
            #pragma unroll
            for (int off = 32; off > 0; off >>= 1)
                s += __shfl_down(s, off);
            if (tau == 0) out[(size_t)b * T_ + t] = s + db0;
        }
    }
}

// ---------------------------------------------------------------------------
// Fallback (no workspace): streaming kernel, correctness only.
// ---------------------------------------------------------------------------
__global__ __launch_bounds__(1024) void lstm_fallback(
        const float* __restrict__ x,  const float* __restrict__ W,
        const float* __restrict__ Um, const float* __restrict__ bias,
        const float* __restrict__ dw, const float* __restrict__ dbp,
        float* __restrict__ out) {
    __shared__ float h_s[U_];
    __shared__ float z_s2[G4];
    __shared__ float pd_s2[U_];
    const int g = threadIdx.x;
    const int b = blockIdx.x;
    const float bg  = bias[g];
    const float dwr = (g < U_) ? dw[g] : 0.f;
    const float db0 = dbp[0];
    float c = 0.f;
    if (g < U_) h_s[g] = 0.f;
    __syncthreads();
    const float* Ucol = Um + g;
    for (int t = 0; t < T_; ++t) {
        float acc = bg;
        const float* xrow = x + ((size_t)b * T_ + t) * D_;
        for (int d = 0; d < D_; ++d) acc += xrow[d] * W[(size_t)d * G4 + g];
        for (int k = 0; k < U_; ++k) acc += h_s[k] * Ucol[(size_t)k * G4];
        z_s2[g] = acc;
        __syncthreads();
        if (g < U_) {
            float ig = sigmoidf_(z_s2[g]);
            float fg = sigmoidf_(z_s2[U_ + g]);
            float gg2 = fmaxf(z_s2[2 * U_ + g], 0.f);
            float og = sigmoidf_(z_s2[3 * U_ + g]);
            c = fg * c + ig * gg2;
            float h = og * fmaxf(c, 0.f);
            h_s[g] = h; pd_s2[g] = h * dwr;
        }
        __syncthreads();
        if (g < 64) {
            float s = pd_s2[g] + pd_s2[g + 64] + pd_s2[g + 128] + pd_s2[g + 192];
            #pragma unroll
            for (int off = 32; off > 0; off >>= 1) s += __shfl_down(s, off);
            if (g == 0) out[(size_t)b * T_ + t] = s + db0;
        }
        __syncthreads();
    }
}

// ---------------------------------------------------------------------------
extern "C" void kernel_launch(void* const* d_in, const int* in_sizes, int n_in,
                              void* d_out, int out_size, void* d_ws, size_t ws_size,
                              hipStream_t stream) {
    const float* x    = (const float*)d_in[0];
    const float* W    = (const float*)d_in[1];
    const float* Um   = (const float*)d_in[2];
    const float* bias = (const float*)d_in[3];
    const float* dw   = (const float*)d_in[4];
    const float* db   = (const float*)d_in[5];
    float* out = (float*)d_out;

    const size_t need = (size_t)T_ * B_ * G4 * sizeof(float);   // 128 MiB
    if (ws_size >= need) {
        float* xz = (float*)d_ws;
        dim3 gridX(G4 / 256, (T_ * B_) / 16);
        xz_kernel<<<gridX, 256, 0, stream>>>(x, W, bias, xz);
        lstm_kernel<<<B_, NT, 0, stream>>>(Um, dw, db, xz, out);
    } else {
        lstm_fallback<<<B_, 1024, 0, stream>>>(x, W, Um, bias, dw, db, out);
    }
}